// Round 12
// baseline (572.647 us; speedup 1.0000x reference)
//
#include <hip/hip_runtime.h>

typedef unsigned short u16;
typedef __attribute__((ext_vector_type(8))) short short8;
typedef __attribute__((ext_vector_type(4))) float f32x4;
typedef __attribute__((ext_vector_type(16))) float f32x16;

// ---- ws layout (bytes) ----
#define OFF_SUMS 0ul              // 6656 floats = 26624
#define OFF_WT   26624ul          // 110592*2 = 221184 : weights bf16, fragment-major (see tr_k)
#define OFF_ASP  247808ul         // 524288*4 = 2097152 : attn_spatial fp32 [pixel]
#define OFF_CONV 2344960ul        // 524288*192*2 = 201326592 : raw conv out bf16 [pixel][192]
// xt (padded NHWC bf16 [8][258][258][64] = 68.2 MB, granule-swizzled) lives in d_out (134 MB);
// k6 overwrites it.
// ---- S (float) offsets ----
#define S_SUM   0      // conv channel sums, 4 shadows x 192
#define S_SSQ   768    // conv channel ssq, 4 shadows x 192
#define M_A1    1920   // per (n*64+c): sum q*k        [512]
#define M_A23   2432   // sum q^2+k^2                  [512]
#define M_A45   2944   // sum q+k                      [512]
#define M_V1    3456   // sum v                        [512]
#define M_V2    3968   // sum v^2                      [512]
#define M_AV    4480   // sum asp*v                    [512]
#define M_AV2   4992   // sum asp*v^2                  [512]
#define M_A2V2  5504   // sum asp^2*v^2                [512]
#define S_NFLOAT 6656

__device__ __forceinline__ float bf2f(u16 v) {
  union { unsigned u; float f; } x; x.u = ((unsigned)v) << 16; return x.f;
}
__device__ __forceinline__ u16 f2bf(float f) {
  union { float f; unsigned u; } x; x.f = f;
  unsigned r = x.u + 0x7fffu + ((x.u >> 16) & 1u);
  return (u16)(r >> 16);
}
// v_rcp_f32: ~1 ulp approx reciprocal; error 1e-7 rel, negligible vs bf16 data path (0.4%).
__device__ __forceinline__ float frcp(float x) { return __builtin_amdgcn_rcpf(x); }
__device__ __forceinline__ float sigmoidf_(float x) { return frcp(1.f + __expf(-x)); }

// ---- DPP adds (all-VALU, zero DS ops) ----
template <int CTRL, int RMASK>
__device__ __forceinline__ float dpp_add(float x) {
  int m = __builtin_amdgcn_update_dpp(0, __builtin_bit_cast(int, x), CTRL, RMASK, 0xf, true);
  return x + __builtin_bit_cast(float, m);
}
// segmented sum over each aligned 8-lane group (R12): quad_perm xor1, quad_perm xor2,
// row_half_mirror (pairs the two halves of each 8). All lanes end with the 8-group total.
__device__ __forceinline__ float seg8sum(float x) {
  x = dpp_add<0xB1, 0xf>(x);   // quad_perm [1,0,3,2]  (xor 1)
  x = dpp_add<0x4E, 0xf>(x);   // quad_perm [2,3,0,1]  (xor 2)
  x = dpp_add<0x141, 0xf>(x);  // row_half_mirror      (pairs lane i <-> 7-i within 8)
  return x;
}

// ---------------- K0: transpose (0..4095) + halo-zero (4096..4103) + repack (4104..4535)
//                   + S-zero (4536) ----------
// xt is PADDED [n][258][258][64] with a 1-px zero border; each 128B pixel row is stored with
// its 16B granules XOR-swizzled by (padded_col & 7). conv_k stages with global_load_lds
// (linear LDS dest + pre-swizzled source + swizzled read).
__global__ void tr_k(const float* __restrict__ x, u16* __restrict__ xt,
                     const float* __restrict__ wq, const float* __restrict__ wk,
                     const float* __restrict__ wv, u16* __restrict__ wt,
                     float* __restrict__ S) {
  const int bid = blockIdx.x;
  const int tid = threadIdx.x;
  if (bid == 4536) {  // ---- S-zero branch ----
    for (int i = tid; i < S_NFLOAT; i += 256) S[i] = 0.f;
    return;
  }
  if (bid >= 4104) {  // ---- repack branch ----
    int i = (bid - 4104) * 256 + tid;
    if (i >= 110592) return;
    int j = i & 7, l = (i >> 3) & 63, kc = (i >> 9) & 3;
    int t2 = i >> 11;              // dydx*6 + ocg
    int ocg = t2 % 6, dydx = t2 / 6;
    int oc = ocg * 32 + (l & 31);
    int ch = kc * 16 + (l >> 5) * 8 + j;
    int cs = oc >> 6, ol = oc & 63;
    const float* src = cs == 0 ? wq : (cs == 1 ? wk : wv);
    wt[i] = f2bf(src[(ol * 64 + ch) * 9 + dydx]);
    return;
  }
  if (bid >= 4096) {  // ---- halo-zero branch: 1-px border of padded image n ----
    const int n = bid - 4096;
    const uint4 z = make_uint4(0u, 0u, 0u, 0u);
    for (int t = tid; t < 8224; t += 256) {
      int cell = t >> 3, g = t & 7;
      int row, col;
      if (cell < 258) { row = 0; col = cell; }
      else if (cell < 516) { row = 257; col = cell - 258; }
      else if (cell < 772) { row = cell - 516 + 1; col = 0; }
      else { row = cell - 772 + 1; col = 257; }
      *(uint4*)(xt + ((long)(n * 258 + row) * 258 + col) * 64 + (g << 3)) = z;
    }
    return;
  }
  // ---- transpose branch (vectorized, R9) ----
  __shared__ u16 t[64][130];
  const int wtile = bid & 1, h = (bid >> 1) & 255, n = bid >> 9;
  const int w0 = wtile << 7;
#pragma unroll
  for (int it = 0; it < 8; ++it) {
    int i = it * 256 + tid;
    int c = i >> 5, w4 = (i & 31) << 2;
    const f32x4 v = *(const f32x4*)(&x[(((long)((n << 6) + c)) << 16) + (h << 8) + w0 + w4]);
    unsigned p0 = (unsigned)f2bf(v[0]) | ((unsigned)f2bf(v[1]) << 16);
    unsigned p1 = (unsigned)f2bf(v[2]) | ((unsigned)f2bf(v[3]) << 16);
    *(unsigned*)(&t[c][w4]) = p0;
    *(unsigned*)(&t[c][w4 + 2]) = p1;
  }
  __syncthreads();
#pragma unroll
  for (int it = 0; it < 4; ++it) {
    int i = it * 256 + tid;
    int g = i & 7, w = i >> 3;          // granule g = channels g*8..g*8+7, col w
    int c8 = g << 3;
    unsigned short u[8];
#pragma unroll
    for (int j = 0; j < 8; ++j) u[j] = t[c8 + j][w];
    uint4 val;
    val.x = (unsigned)u[0] | ((unsigned)u[1] << 16);
    val.y = (unsigned)u[2] | ((unsigned)u[3] << 16);
    val.z = (unsigned)u[4] | ((unsigned)u[5] << 16);
    val.w = (unsigned)u[6] | ((unsigned)u[7] << 16);
    const int pw = w0 + w + 1;          // padded col
    const int gs = g ^ (pw & 7);        // pre-swizzled granule
    *(uint4*)(xt + ((long)(n * 258 + h + 1) * 258 + pw) * 64 + (gs << 3)) = val;
  }
}

// ---------------- K1: fused QKV conv3x3 as implicit GEMM (MFMA bf16) + channel stats ----------------
// R11 (unchanged in R12, control): global_load_lds staging + hoisted tap-(0,0) B prefetch.
__global__ __launch_bounds__(256, 2) void conv_k(const u16* __restrict__ xt,
                                                 const u16* __restrict__ wt,
                                                 u16* __restrict__ conv,
                                                 float* __restrict__ S) {
  __shared__ u16 lx[3 * 8704];  // 3 strips * 136 px * 64 ch = 52224 B (px 130..135 unused)
  const int bid = blockIdx.x;
  const int wtile = bid & 1, h = (bid >> 1) & 255, n = bid >> 9;
  const int w0 = wtile << 7;
  const int tid = threadIdx.x;
  const int lane = tid & 63, wave = tid >> 6;
  const int l31 = lane & 31, half = lane >> 5;
  const int wm = wave & 1, wn = wave >> 1;  // wm: px half (64), wn: oc group (96)
  {
    // strip s: padded row h+s (= global rows h-1..h+1), padded cols w0.. (= global w0-1..)
    const long rowbase = ((long)(n * 258 + h) * 258 + w0) * 64;
    for (int c = wave; c < 51; c += 4) {
      const int s = (c >= 34) ? 2 : (c >= 17 ? 1 : 0);
      const int lc = c - s * 17;
      const int loff = s * 8704 + lc * 512 + lane * 8;
      const long goff = rowbase + (long)s * 16512 + lc * 512 + lane * 8;  // 258*64=16512
      __builtin_amdgcn_global_load_lds(
          (const __attribute__((address_space(1))) unsigned int*)(xt + goff),
          (__attribute__((address_space(3))) unsigned int*)(&lx[loff]), 16, 0, 0);
    }
  }
  // prefetch tap-(0,0) B fragments before the barrier (independent of LDS staging)
  short8 bfr0[3][4];
#pragma unroll
  for (int nt = 0; nt < 3; ++nt)
#pragma unroll
    for (int kc = 0; kc < 4; ++kc)
      bfr0[nt][kc] = *(const short8*)(wt + ((wn * 3 + nt) * 4 + kc) * 512 + lane * 8);
  __syncthreads();
  f32x16 acc[3][2];
#pragma unroll
  for (int a = 0; a < 3; ++a)
#pragma unroll
    for (int b = 0; b < 2; ++b)
#pragma unroll
      for (int e = 0; e < 16; ++e) acc[a][b][e] = 0.f;

#pragma unroll
  for (int dy = 0; dy < 3; ++dy) {
#pragma unroll
    for (int dx = 0; dx < 3; ++dx) {
      const u16* wp = wt + (dy * 3 + dx) * 12288;
      short8 bfr[3][4];
#pragma unroll
      for (int nt = 0; nt < 3; ++nt)
#pragma unroll
        for (int kc = 0; kc < 4; ++kc)
          bfr[nt][kc] = (dy == 0 && dx == 0) ? bfr0[nt][kc]
                        : *(const short8*)(wp + ((wn * 3 + nt) * 4 + kc) * 512 + lane * 8);
#pragma unroll
      for (int kc = 0; kc < 4; ++kc) {
        short8 afr[2];
#pragma unroll
        for (int mt = 0; mt < 2; ++mt) {
          const int px = wm * 64 + mt * 32 + l31 + dx;       // staged col (0..129)
          const int chb = kc * 16 + half * 8;                // k-slice base channel
          int idx = ((px << 6) + chb) ^ ((px & 7) << 3);
          afr[mt] = *(const short8*)(&lx[dy * 8704 + idx]);
        }
#pragma unroll
        for (int mt = 0; mt < 2; ++mt)
#pragma unroll
          for (int nt = 0; nt < 3; ++nt)
            acc[nt][mt] = __builtin_amdgcn_mfma_f32_32x32x16_bf16(afr[mt], bfr[nt][kc], acc[nt][mt], 0, 0, 0);
      }
    }
  }
  // epilogue: C col = l31 (oc), row = (r&3) + 8*(r>>2) + 4*half (px); store bf16 [pixel][192]
  const long pix0 = (long)bid * 128 + wm * 64;
#pragma unroll
  for (int nt = 0; nt < 3; ++nt) {
    const int oc = wn * 96 + nt * 32 + l31;
#pragma unroll
    for (int mt = 0; mt < 2; ++mt) {
      const long pxb = pix0 + mt * 32 + half * 4;
#pragma unroll
      for (int rq = 0; rq < 4; ++rq)
#pragma unroll
        for (int rr = 0; rr < 4; ++rr) {
          const long px = pxb + rr + 8 * rq;
          conv[px * 192 + oc] = f2bf(acc[nt][mt][rq * 4 + rr]);
        }
    }
  }
  // fused per-channel stats
  const int sh = (bid & 3) * 192;
#pragma unroll
  for (int nt = 0; nt < 3; ++nt) {
    float s = 0.f, ss = 0.f;
#pragma unroll
    for (int mt = 0; mt < 2; ++mt)
#pragma unroll
      for (int r = 0; r < 16; ++r) {
        float x = acc[nt][mt][r];
        s += x; ss += x * x;
      }
    s += __shfl_xor(s, 32); ss += __shfl_xor(ss, 32);
    if (lane < 32) {
      const int oc = wn * 96 + nt * 32 + lane;
      atomicAdd(&S[S_SUM + sh + oc], s);
      atomicAdd(&S[S_SSQ + sh + oc], ss);
    }
  }
}

// ---------------- K3: BN+sigmoid q,k,v; asp per pixel; 8 moments per (n,c) ----------------
// R12 rewrite (G13): lane = (pixel-group g = lane>>3, channel-slot cs = lane&7).
// Loads: 3x short8 per lane-iter (12 VMEM/thread, was 96 scalar u16). Pixel reduce over
// 64 ch = per-lane 8-ch partial + 3 segmented DPP hops (was 18 wave-wide hops PER PIXEL).
// Moments: per-channel f32[8] register arrays (fully unrolled), folded g^1 via row_ror:8
// then 32KB LDS partials + 64-thread finisher.
__global__ void k3_k(const u16* __restrict__ conv, float* __restrict__ S, float* __restrict__ asp,
                     const float* __restrict__ gq, const float* __restrict__ bq,
                     const float* __restrict__ gk, const float* __restrict__ bk,
                     const float* __restrict__ gv, const float* __restrict__ bv) {
  __shared__ float scb[192], bib[192];
  __shared__ float mred[4][4][8][8][8];  // [wave][g>>1][cs][moment][j] = 32 KB
  const int tid = threadIdx.x, lane = tid & 63, wave = tid >> 6;
  const int bid = blockIdx.x;          // 4096 blocks x 128 px
  const int n = bid >> 9;
  const int g = lane >> 3, cs = lane & 7;
  const long p0 = (long)bid * 128 + wave * 32;
  if (tid < 192) {
    int cv = tid >> 6, c = tid & 63;
    float gg = cv == 0 ? gq[c] : (cv == 1 ? gk[c] : gv[c]);
    float b = cv == 0 ? bq[c] : (cv == 1 ? bk[c] : bv[c]);
    float sm = 0.f, sq2 = 0.f;
#pragma unroll
    for (int sh = 0; sh < 4; ++sh) { sm += S[S_SUM + sh * 192 + tid]; sq2 += S[S_SSQ + sh * 192 + tid]; }
    const float inv = 1.f / 524288.f;
    float mean = sm * inv;
    float var = sq2 * inv - mean * mean;
    float rstd = rsqrtf(var + 1e-5f);
    float sc = gg * rstd;
    scb[tid] = sc;
    bib[tid] = b - mean * sc;
  }
  __syncthreads();
  float sq[8], bq2[8], sk[8], bk2[8], sv[8], bv2[8];
#pragma unroll
  for (int j = 0; j < 8; ++j) {
    sq[j] = scb[cs * 8 + j];        bq2[j] = bib[cs * 8 + j];
    sk[j] = scb[64 + cs * 8 + j];   bk2[j] = bib[64 + cs * 8 + j];
    sv[j] = scb[128 + cs * 8 + j];  bv2[j] = bib[128 + cs * 8 + j];
  }
  float A1[8], A23[8], A45[8], V1[8], V2[8], AV[8], AV2[8], A2V2[8];
#pragma unroll
  for (int j = 0; j < 8; ++j) {
    A1[j] = A23[j] = A45[j] = V1[j] = V2[j] = AV[j] = AV2[j] = A2V2[j] = 0.f;
  }
#pragma unroll
  for (int i = 0; i < 4; ++i) {
    const long p = p0 + i * 8 + g;
    const u16* row = conv + p * 192;
    short8 qv = *(const short8*)(row + cs * 8);
    short8 kv = *(const short8*)(row + 64 + cs * 8);
    short8 vv = *(const short8*)(row + 128 + cs * 8);
    float s1l = 0.f, s23l = 0.f, s45l = 0.f;
    float vf[8];
#pragma unroll
    for (int j = 0; j < 8; ++j) {
      float qf = sigmoidf_(bf2f((u16)qv[j]) * sq[j] + bq2[j]);
      float kf = sigmoidf_(bf2f((u16)kv[j]) * sk[j] + bk2[j]);
      vf[j] = sigmoidf_(bf2f((u16)vv[j]) * sv[j] + bv2[j]);
      float p1 = qf * kf, p23 = qf * qf + kf * kf, p45 = qf + kf;
      A1[j] += p1; A23[j] += p23; A45[j] += p45;
      s1l += p1; s23l += p23; s45l += p45;
    }
    float s1 = seg8sum(s1l);
    float s23 = seg8sum(s23l);
    float s45 = seg8sum(s45l);
    const float sm = 1e-5f;
    float t1 = (s1 + sm) * frcp(s23 - s1 + sm);
    float t2 = (64.f - s45 + s1 + sm) * frcp(64.f - s45 + s23 - s1 + sm);
    float a = 0.5f * (t1 + t2);
    if (cs == 0) asp[p] = a;
#pragma unroll
    for (int j = 0; j < 8; ++j) {
      float v = vf[j], av = a * v;
      V1[j] += v; V2[j] += v * v; AV[j] += av; AV2[j] += av * v; A2V2[j] += av * av;
    }
  }
  // fold g with g^1 via row_ror:8 (VALU; rotate-by-8 on a 16-ring == lane^8)
#pragma unroll
  for (int j = 0; j < 8; ++j) {
    A1[j] = dpp_add<0x128, 0xf>(A1[j]);   A23[j] = dpp_add<0x128, 0xf>(A23[j]);
    A45[j] = dpp_add<0x128, 0xf>(A45[j]); V1[j] = dpp_add<0x128, 0xf>(V1[j]);
    V2[j] = dpp_add<0x128, 0xf>(V2[j]);   AV[j] = dpp_add<0x128, 0xf>(AV[j]);
    AV2[j] = dpp_add<0x128, 0xf>(AV2[j]); A2V2[j] = dpp_add<0x128, 0xf>(A2V2[j]);
  }
  if ((g & 1) == 0) {
    float* dst = &mred[wave][g >> 1][cs][0][0];
#pragma unroll
    for (int j = 0; j < 8; ++j) {
      dst[0 * 8 + j] = A1[j];  dst[1 * 8 + j] = A23[j]; dst[2 * 8 + j] = A45[j];
      dst[3 * 8 + j] = V1[j];  dst[4 * 8 + j] = V2[j];  dst[5 * 8 + j] = AV[j];
      dst[6 * 8 + j] = AV2[j]; dst[7 * 8 + j] = A2V2[j];
    }
  }
  __syncthreads();
  if (tid < 64) {
    const int mb[8] = {M_A1, M_A23, M_A45, M_V1, M_V2, M_AV, M_AV2, M_A2V2};
    const int csf = tid >> 3, jf = tid & 7;
#pragma unroll
    for (int m = 0; m < 8; ++m) {
      float t = 0.f;
#pragma unroll
      for (int w = 0; w < 4; ++w)
#pragma unroll
        for (int gh = 0; gh < 4; ++gh) t += mred[w][gh][csf][m][jf];
      atomicAdd(&S[mb[m] + n * 64 + tid], t);
    }
  }
}

// ---------------- K6: attention -> final BN -> NCHW fp32 out (LDS transpose) ----------------
// R12 (G13): lane = (g, cs); v-loads short8 (4 VMEM/thread, was 32 scalar u16); per-channel
// params hoisted to registers; LDS tile [128][68] for 16B-aligned f32x4 stores.
// 128B-run output stores (R11) kept.
__global__ void k6_k(const u16* __restrict__ conv, const float* __restrict__ S,
                     const float* __restrict__ asp, float* __restrict__ out,
                     const float* __restrict__ gv, const float* __restrict__ bv,
                     const float* __restrict__ gn, const float* __restrict__ bn_) {
  __shared__ float t[128][68];
  __shared__ float svv[64], bvv[64], achb[64], sAv[64], bAv[64];
  const int tid = threadIdx.x, lane = tid & 63, wave = tid >> 6;
  const int n = blockIdx.x >> 9;
  const int hw0 = (blockIdx.x & 511) << 7;
  const long P0 = (long)blockIdx.x * 128;
  if (tid < 64) {
    const float inv = 1.f / 524288.f;
    float sm = 0.f, sq2 = 0.f;
#pragma unroll
    for (int sh = 0; sh < 4; ++sh) {
      sm += S[S_SUM + sh * 192 + 128 + tid];
      sq2 += S[S_SSQ + sh * 192 + 128 + tid];
    }
    float mean = sm * inv;
    float var = sq2 * inv - mean * mean;
    float rstd = rsqrtf(var + 1e-5f);
    float sv = gv[tid] * rstd;
    svv[tid] = sv;
    bvv[tid] = bv[tid] - mean * sv;
    const float smc = 1e-5f, cnt = 65536.f;
    float s1 = 0.f, s2 = 0.f, myach = 0.f;
#pragma unroll
    for (int nn = 0; nn < 8; ++nn) {
      int idx = nn * 64 + tid;
      float A1 = S[M_A1 + idx], A23 = S[M_A23 + idx], A45 = S[M_A45 + idx];
      float t1 = (A1 + smc) / (A23 - A1 + smc);
      float t2 = (cnt - A45 + A1 + smc) / (cnt - A45 + A23 - A1 + smc);
      float ach = 0.5f * (t1 + t2);
      if (nn == n) myach = ach;
      s1 += 0.5f * (S[M_AV + idx] + ach * S[M_V1 + idx]);
      s2 += 0.25f * (S[M_A2V2 + idx] + 2.f * ach * S[M_AV2 + idx] + ach * ach * S[M_V2 + idx]);
    }
    float mean2 = s1 * inv;
    float var2 = s2 * inv - mean2 * mean2;
    float rstd2 = rsqrtf(var2 + 1e-5f);
    float sA = gn[tid] * rstd2;
    sAv[tid] = sA;
    bAv[tid] = bn_[tid] - mean2 * sA;
    achb[tid] = myach;
  }
  __syncthreads();
  const int g = lane >> 3, cs = lane & 7;
  float sv8[8], bv8[8], av8[8], sA8[8], bA8[8];
#pragma unroll
  for (int j = 0; j < 8; ++j) {
    int c = cs * 8 + j;
    sv8[j] = svv[c]; bv8[j] = bvv[c]; av8[j] = achb[c]; sA8[j] = sAv[c]; bA8[j] = bAv[c];
  }
#pragma unroll
  for (int i = 0; i < 4; ++i) {
    const int px = i * 32 + wave * 8 + g;
    const long p = P0 + px;
    short8 vv = *(const short8*)(conv + p * 192 + 128 + cs * 8);
    float aspv = asp[p];
    f32x4 lo, hi;
#pragma unroll
    for (int j = 0; j < 8; ++j) {
      float v = sigmoidf_(bf2f((u16)vv[j]) * sv8[j] + bv8[j]);
      float att = 0.5f * (aspv + av8[j]) * v;
      float o = att * sA8[j] + bA8[j];
      if (j < 4) lo[j] = o; else hi[j - 4] = o;
    }
    *(f32x4*)(&t[px][cs * 8]) = lo;
    *(f32x4*)(&t[px][cs * 8 + 4]) = hi;
  }
  __syncthreads();
  const int c0 = tid >> 3, sub = tid & 7;   // 32 channels per pass, 8 x 16B = 128B runs
#pragma unroll
  for (int cl = 0; cl < 2; ++cl) {
    const int c = c0 + 32 * cl;
    const long plane = ((long)((n << 6) + c)) << 16;
#pragma unroll
    for (int i = 0; i < 4; ++i) {
      const int pst = (i * 8 + sub) << 2;
      f32x4 vbuf;
#pragma unroll
      for (int j = 0; j < 4; ++j) vbuf[j] = t[pst + j][c];
      *(f32x4*)(&out[plane + hw0 + pst]) = vbuf;
    }
  }
}

extern "C" void kernel_launch(void* const* d_in, const int* in_sizes, int n_in,
                              void* d_out, int out_size, void* d_ws, size_t ws_size,
                              hipStream_t stream) {
  (void)in_sizes; (void)n_in; (void)out_size; (void)ws_size;
  const float* x  = (const float*)d_in[0];
  const float* wq = (const float*)d_in[1];
  const float* gq = (const float*)d_in[2];
  const float* bq = (const float*)d_in[3];
  const float* wk = (const float*)d_in[4];
  const float* gk = (const float*)d_in[5];
  const float* bk = (const float*)d_in[6];
  const float* wv = (const float*)d_in[7];
  const float* gv = (const float*)d_in[8];
  const float* bv = (const float*)d_in[9];
  const float* gn = (const float*)d_in[10];
  const float* bn_ = (const float*)d_in[11];
  char* ws = (char*)d_ws;
  float* S   = (float*)(ws + OFF_SUMS);
  u16* wt    = (u16*)(ws + OFF_WT);
  float* asp = (float*)(ws + OFF_ASP);
  u16* conv  = (u16*)(ws + OFF_CONV);
  float* out = (float*)d_out;
  u16* xt  = (u16*)d_out;  // padded pre-swizzled bf16 scratch in d_out; overwritten by k6_k

  tr_k<<<4537, 256, 0, stream>>>(x, xt, wq, wk, wv, wt, S);
  conv_k<<<4096, 256, 0, stream>>>(xt, wt, conv, S);
  k3_k<<<4096, 256, 0, stream>>>(conv, S, asp, gq, bq, gk, bk, gv, bv);
  k6_k<<<4096, 256, 0, stream>>>(conv, S, asp, out, gv, bv, gn, bn_);
}

// Round 13
// 568.822 us; speedup vs baseline: 1.0067x; 1.0067x over previous
//
#include <hip/hip_runtime.h>

typedef unsigned short u16;
typedef __attribute__((ext_vector_type(4))) short short4v;
typedef __attribute__((ext_vector_type(8))) short short8;
typedef __attribute__((ext_vector_type(4))) float f32x4;
typedef __attribute__((ext_vector_type(16))) float f32x16;

// ---- ws layout (bytes) ----
#define OFF_SUMS 0ul              // 6656 floats = 26624
#define OFF_WT   26624ul          // 110592*2 = 221184 : weights bf16, fragment-major (see tr_k)
#define OFF_ASP  247808ul         // 524288*4 = 2097152 : attn_spatial fp32 [pixel]
#define OFF_CONV 2344960ul        // 524288*192*2 = 201326592 : raw conv out bf16 [pixel][192]
// xt (padded NHWC bf16 [8][258][258][64] = 68.2 MB, granule-swizzled) lives in d_out (134 MB);
// k6 overwrites it.
// ---- S (float) offsets ----
#define S_SUM   0      // conv channel sums, 4 shadows x 192
#define S_SSQ   768    // conv channel ssq, 4 shadows x 192
#define M_A1    1920   // per (n*64+c): sum q*k        [512]
#define M_A23   2432   // sum q^2+k^2                  [512]
#define M_A45   2944   // sum q+k                      [512]
#define M_V1    3456   // sum v                        [512]
#define M_V2    3968   // sum v^2                      [512]
#define M_AV    4480   // sum asp*v                    [512]
#define M_AV2   4992   // sum asp*v^2                  [512]
#define M_A2V2  5504   // sum asp^2*v^2                [512]
#define S_NFLOAT 6656

__device__ __forceinline__ float bf2f(u16 v) {
  union { unsigned u; float f; } x; x.u = ((unsigned)v) << 16; return x.f;
}
__device__ __forceinline__ u16 f2bf(float f) {
  union { float f; unsigned u; } x; x.f = f;
  unsigned r = x.u + 0x7fffu + ((x.u >> 16) & 1u);
  return (u16)(r >> 16);
}
// v_rcp_f32: ~1 ulp approx reciprocal; error 1e-7 rel, negligible vs bf16 data path (0.4%).
__device__ __forceinline__ float frcp(float x) { return __builtin_amdgcn_rcpf(x); }
__device__ __forceinline__ float sigmoidf_(float x) { return frcp(1.f + __expf(-x)); }

// ---- DPP adds (all-VALU, zero DS ops) ----
template <int CTRL, int RMASK>
__device__ __forceinline__ float dpp_add(float x) {
  int m = __builtin_amdgcn_update_dpp(0, __builtin_bit_cast(int, x), CTRL, RMASK, 0xf, true);
  return x + __builtin_bit_cast(float, m);
}
// segmented sum over each aligned 16-lane group (R13): xor1, xor2, half_mirror (8-group
// total), row_mirror (fold the two 8-halves of the 16-row). All 16 lanes end with the total.
__device__ __forceinline__ float seg16sum(float x) {
  x = dpp_add<0xB1, 0xf>(x);   // quad_perm [1,0,3,2]  (xor 1)
  x = dpp_add<0x4E, 0xf>(x);   // quad_perm [2,3,0,1]  (xor 2)
  x = dpp_add<0x141, 0xf>(x);  // row_half_mirror      (i <-> 7-i within 8)
  x = dpp_add<0x140, 0xf>(x);  // row_mirror           (i <-> 15-i within 16)
  return x;
}

// ---------------- K0: transpose (0..4095) + halo-zero (4096..4103) + repack (4104..4535)
//                   + S-zero (4536) ----------
// xt is PADDED [n][258][258][64] with a 1-px zero border; each 128B pixel row is stored with
// its 16B granules XOR-swizzled by (padded_col & 7). conv_k stages with global_load_lds
// (linear LDS dest + pre-swizzled source + swizzled read).
__global__ void tr_k(const float* __restrict__ x, u16* __restrict__ xt,
                     const float* __restrict__ wq, const float* __restrict__ wk,
                     const float* __restrict__ wv, u16* __restrict__ wt,
                     float* __restrict__ S) {
  const int bid = blockIdx.x;
  const int tid = threadIdx.x;
  if (bid == 4536) {  // ---- S-zero branch ----
    for (int i = tid; i < S_NFLOAT; i += 256) S[i] = 0.f;
    return;
  }
  if (bid >= 4104) {  // ---- repack branch ----
    int i = (bid - 4104) * 256 + tid;
    if (i >= 110592) return;
    int j = i & 7, l = (i >> 3) & 63, kc = (i >> 9) & 3;
    int t2 = i >> 11;              // dydx*6 + ocg
    int ocg = t2 % 6, dydx = t2 / 6;
    int oc = ocg * 32 + (l & 31);
    int ch = kc * 16 + (l >> 5) * 8 + j;
    int cs = oc >> 6, ol = oc & 63;
    const float* src = cs == 0 ? wq : (cs == 1 ? wk : wv);
    wt[i] = f2bf(src[(ol * 64 + ch) * 9 + dydx]);
    return;
  }
  if (bid >= 4096) {  // ---- halo-zero branch: 1-px border of padded image n ----
    const int n = bid - 4096;
    const uint4 z = make_uint4(0u, 0u, 0u, 0u);
    for (int t = tid; t < 8224; t += 256) {
      int cell = t >> 3, g = t & 7;
      int row, col;
      if (cell < 258) { row = 0; col = cell; }
      else if (cell < 516) { row = 257; col = cell - 258; }
      else if (cell < 772) { row = cell - 516 + 1; col = 0; }
      else { row = cell - 772 + 1; col = 257; }
      *(uint4*)(xt + ((long)(n * 258 + row) * 258 + col) * 64 + (g << 3)) = z;
    }
    return;
  }
  // ---- transpose branch (vectorized, R9) ----
  __shared__ u16 t[64][130];
  const int wtile = bid & 1, h = (bid >> 1) & 255, n = bid >> 9;
  const int w0 = wtile << 7;
#pragma unroll
  for (int it = 0; it < 8; ++it) {
    int i = it * 256 + tid;
    int c = i >> 5, w4 = (i & 31) << 2;
    const f32x4 v = *(const f32x4*)(&x[(((long)((n << 6) + c)) << 16) + (h << 8) + w0 + w4]);
    unsigned p0 = (unsigned)f2bf(v[0]) | ((unsigned)f2bf(v[1]) << 16);
    unsigned p1 = (unsigned)f2bf(v[2]) | ((unsigned)f2bf(v[3]) << 16);
    *(unsigned*)(&t[c][w4]) = p0;
    *(unsigned*)(&t[c][w4 + 2]) = p1;
  }
  __syncthreads();
#pragma unroll
  for (int it = 0; it < 4; ++it) {
    int i = it * 256 + tid;
    int g = i & 7, w = i >> 3;          // granule g = channels g*8..g*8+7, col w
    int c8 = g << 3;
    unsigned short u[8];
#pragma unroll
    for (int j = 0; j < 8; ++j) u[j] = t[c8 + j][w];
    uint4 val;
    val.x = (unsigned)u[0] | ((unsigned)u[1] << 16);
    val.y = (unsigned)u[2] | ((unsigned)u[3] << 16);
    val.z = (unsigned)u[4] | ((unsigned)u[5] << 16);
    val.w = (unsigned)u[6] | ((unsigned)u[7] << 16);
    const int pw = w0 + w + 1;          // padded col
    const int gs = g ^ (pw & 7);        // pre-swizzled granule
    *(uint4*)(xt + ((long)(n * 258 + h + 1) * 258 + pw) * 64 + (gs << 3)) = val;
  }
}

// ---------------- K1: fused QKV conv3x3 as implicit GEMM (MFMA bf16) + channel stats ----------------
// R11 (unchanged, control): global_load_lds staging + hoisted tap-(0,0) B prefetch.
__global__ __launch_bounds__(256, 2) void conv_k(const u16* __restrict__ xt,
                                                 const u16* __restrict__ wt,
                                                 u16* __restrict__ conv,
                                                 float* __restrict__ S) {
  __shared__ u16 lx[3 * 8704];  // 3 strips * 136 px * 64 ch = 52224 B (px 130..135 unused)
  const int bid = blockIdx.x;
  const int wtile = bid & 1, h = (bid >> 1) & 255, n = bid >> 9;
  const int w0 = wtile << 7;
  const int tid = threadIdx.x;
  const int lane = tid & 63, wave = tid >> 6;
  const int l31 = lane & 31, half = lane >> 5;
  const int wm = wave & 1, wn = wave >> 1;  // wm: px half (64), wn: oc group (96)
  {
    // strip s: padded row h+s (= global rows h-1..h+1), padded cols w0.. (= global w0-1..)
    const long rowbase = ((long)(n * 258 + h) * 258 + w0) * 64;
    for (int c = wave; c < 51; c += 4) {
      const int s = (c >= 34) ? 2 : (c >= 17 ? 1 : 0);
      const int lc = c - s * 17;
      const int loff = s * 8704 + lc * 512 + lane * 8;
      const long goff = rowbase + (long)s * 16512 + lc * 512 + lane * 8;  // 258*64=16512
      __builtin_amdgcn_global_load_lds(
          (const __attribute__((address_space(1))) unsigned int*)(xt + goff),
          (__attribute__((address_space(3))) unsigned int*)(&lx[loff]), 16, 0, 0);
    }
  }
  // prefetch tap-(0,0) B fragments before the barrier (independent of LDS staging)
  short8 bfr0[3][4];
#pragma unroll
  for (int nt = 0; nt < 3; ++nt)
#pragma unroll
    for (int kc = 0; kc < 4; ++kc)
      bfr0[nt][kc] = *(const short8*)(wt + ((wn * 3 + nt) * 4 + kc) * 512 + lane * 8);
  __syncthreads();
  f32x16 acc[3][2];
#pragma unroll
  for (int a = 0; a < 3; ++a)
#pragma unroll
    for (int b = 0; b < 2; ++b)
#pragma unroll
      for (int e = 0; e < 16; ++e) acc[a][b][e] = 0.f;

#pragma unroll
  for (int dy = 0; dy < 3; ++dy) {
#pragma unroll
    for (int dx = 0; dx < 3; ++dx) {
      const u16* wp = wt + (dy * 3 + dx) * 12288;
      short8 bfr[3][4];
#pragma unroll
      for (int nt = 0; nt < 3; ++nt)
#pragma unroll
        for (int kc = 0; kc < 4; ++kc)
          bfr[nt][kc] = (dy == 0 && dx == 0) ? bfr0[nt][kc]
                        : *(const short8*)(wp + ((wn * 3 + nt) * 4 + kc) * 512 + lane * 8);
#pragma unroll
      for (int kc = 0; kc < 4; ++kc) {
        short8 afr[2];
#pragma unroll
        for (int mt = 0; mt < 2; ++mt) {
          const int px = wm * 64 + mt * 32 + l31 + dx;       // staged col (0..129)
          const int chb = kc * 16 + half * 8;                // k-slice base channel
          int idx = ((px << 6) + chb) ^ ((px & 7) << 3);
          afr[mt] = *(const short8*)(&lx[dy * 8704 + idx]);
        }
#pragma unroll
        for (int mt = 0; mt < 2; ++mt)
#pragma unroll
          for (int nt = 0; nt < 3; ++nt)
            acc[nt][mt] = __builtin_amdgcn_mfma_f32_32x32x16_bf16(afr[mt], bfr[nt][kc], acc[nt][mt], 0, 0, 0);
      }
    }
  }
  // epilogue: C col = l31 (oc), row = (r&3) + 8*(r>>2) + 4*half (px); store bf16 [pixel][192]
  const long pix0 = (long)bid * 128 + wm * 64;
#pragma unroll
  for (int nt = 0; nt < 3; ++nt) {
    const int oc = wn * 96 + nt * 32 + l31;
#pragma unroll
    for (int mt = 0; mt < 2; ++mt) {
      const long pxb = pix0 + mt * 32 + half * 4;
#pragma unroll
      for (int rq = 0; rq < 4; ++rq)
#pragma unroll
        for (int rr = 0; rr < 4; ++rr) {
          const long px = pxb + rr + 8 * rq;
          conv[px * 192 + oc] = f2bf(acc[nt][mt][rq * 4 + rr]);
        }
    }
  }
  // fused per-channel stats
  const int sh = (bid & 3) * 192;
#pragma unroll
  for (int nt = 0; nt < 3; ++nt) {
    float s = 0.f, ss = 0.f;
#pragma unroll
    for (int mt = 0; mt < 2; ++mt)
#pragma unroll
      for (int r = 0; r < 16; ++r) {
        float x = acc[nt][mt][r];
        s += x; ss += x * x;
      }
    s += __shfl_xor(s, 32); ss += __shfl_xor(ss, 32);
    if (lane < 32) {
      const int oc = wn * 96 + nt * 32 + lane;
      atomicAdd(&S[S_SUM + sh + oc], s);
      atomicAdd(&S[S_SSQ + sh + oc], ss);
    }
  }
}

// ---------------- K3: BN+sigmoid q,k,v; asp per pixel; 8 moments per (n,c) ----------------
// R13: R12's vectorized structure with 4 channels/lane to kill the spill (R12: VGPR pinned
// at 64, ~230 MB scratch writes). lane = (g = lane>>4 pixel group, cs = lane&15 4-ch slot);
// short4 loads (8B/lane coalesced); per-thread state ~60 floats; launch_bounds(256,4)
// caps 128 VGPR. Pixel reduce = 4 DPP hops. mred stride 36 floats -> 2-way banks (free).
__global__ __launch_bounds__(256, 4) void k3_k(const u16* __restrict__ conv, float* __restrict__ S,
                     float* __restrict__ asp,
                     const float* __restrict__ gq, const float* __restrict__ bq,
                     const float* __restrict__ gk, const float* __restrict__ bk,
                     const float* __restrict__ gv, const float* __restrict__ bv) {
  __shared__ float scb[192], bib[192];
  __shared__ float mred[16][16][36];   // [wave*4+g][cs][8 moments x 4 j (+pad)] = 36864 B
  const int tid = threadIdx.x, lane = tid & 63, wave = tid >> 6;
  const int bid = blockIdx.x;          // 4096 blocks x 128 px
  const int n = bid >> 9;
  const int g = lane >> 4, cs = lane & 15;
  const long p0 = (long)bid * 128 + wave * 32;
  if (tid < 192) {
    int cv = tid >> 6, c = tid & 63;
    float gg = cv == 0 ? gq[c] : (cv == 1 ? gk[c] : gv[c]);
    float b = cv == 0 ? bq[c] : (cv == 1 ? bk[c] : bv[c]);
    float sm = 0.f, sq2 = 0.f;
#pragma unroll
    for (int sh = 0; sh < 4; ++sh) { sm += S[S_SUM + sh * 192 + tid]; sq2 += S[S_SSQ + sh * 192 + tid]; }
    const float inv = 1.f / 524288.f;
    float mean = sm * inv;
    float var = sq2 * inv - mean * mean;
    float rstd = rsqrtf(var + 1e-5f);
    float sc = gg * rstd;
    scb[tid] = sc;
    bib[tid] = b - mean * sc;
  }
  __syncthreads();
  float sq[4], bq2[4], sk[4], bk2[4], sv[4], bv2[4];
#pragma unroll
  for (int j = 0; j < 4; ++j) {
    sq[j] = scb[cs * 4 + j];        bq2[j] = bib[cs * 4 + j];
    sk[j] = scb[64 + cs * 4 + j];   bk2[j] = bib[64 + cs * 4 + j];
    sv[j] = scb[128 + cs * 4 + j];  bv2[j] = bib[128 + cs * 4 + j];
  }
  float A1[4], A23[4], A45[4], V1[4], V2[4], AV[4], AV2[4], A2V2[4];
#pragma unroll
  for (int j = 0; j < 4; ++j) {
    A1[j] = A23[j] = A45[j] = V1[j] = V2[j] = AV[j] = AV2[j] = A2V2[j] = 0.f;
  }
#pragma unroll
  for (int i = 0; i < 8; ++i) {
    const long p = p0 + i * 4 + g;
    const u16* row = conv + p * 192;
    short4v qv = *(const short4v*)(row + cs * 4);
    short4v kv = *(const short4v*)(row + 64 + cs * 4);
    short4v vv = *(const short4v*)(row + 128 + cs * 4);
    float s1l = 0.f, s23l = 0.f, s45l = 0.f;
    float vf[4];
#pragma unroll
    for (int j = 0; j < 4; ++j) {
      float qf = sigmoidf_(bf2f((u16)qv[j]) * sq[j] + bq2[j]);
      float kf = sigmoidf_(bf2f((u16)kv[j]) * sk[j] + bk2[j]);
      vf[j] = sigmoidf_(bf2f((u16)vv[j]) * sv[j] + bv2[j]);
      float p1 = qf * kf, p23 = qf * qf + kf * kf, p45 = qf + kf;
      A1[j] += p1; A23[j] += p23; A45[j] += p45;
      s1l += p1; s23l += p23; s45l += p45;
    }
    float s1 = seg16sum(s1l);
    float s23 = seg16sum(s23l);
    float s45 = seg16sum(s45l);
    const float sm = 1e-5f;
    float t1 = (s1 + sm) * frcp(s23 - s1 + sm);
    float t2 = (64.f - s45 + s1 + sm) * frcp(64.f - s45 + s23 - s1 + sm);
    float a = 0.5f * (t1 + t2);
    if (cs == 0) asp[p] = a;
#pragma unroll
    for (int j = 0; j < 4; ++j) {
      float v = vf[j], av = a * v;
      V1[j] += v; V2[j] += v * v; AV[j] += av; AV2[j] += av * v; A2V2[j] += av * av;
    }
  }
  {
    float* dst = &mred[wave * 4 + g][cs][0];
    *(f32x4*)(dst + 0)  = (f32x4){A1[0], A1[1], A1[2], A1[3]};
    *(f32x4*)(dst + 4)  = (f32x4){A23[0], A23[1], A23[2], A23[3]};
    *(f32x4*)(dst + 8)  = (f32x4){A45[0], A45[1], A45[2], A45[3]};
    *(f32x4*)(dst + 12) = (f32x4){V1[0], V1[1], V1[2], V1[3]};
    *(f32x4*)(dst + 16) = (f32x4){V2[0], V2[1], V2[2], V2[3]};
    *(f32x4*)(dst + 20) = (f32x4){AV[0], AV[1], AV[2], AV[3]};
    *(f32x4*)(dst + 24) = (f32x4){AV2[0], AV2[1], AV2[2], AV2[3]};
    *(f32x4*)(dst + 28) = (f32x4){A2V2[0], A2V2[1], A2V2[2], A2V2[3]};
  }
  __syncthreads();
  if (tid < 64) {
    const int mb[8] = {M_A1, M_A23, M_A45, M_V1, M_V2, M_AV, M_AV2, M_A2V2};
    const int csf = tid >> 2, jf = tid & 3;
#pragma unroll
    for (int m = 0; m < 8; ++m) {
      float t = 0.f;
#pragma unroll
      for (int wg = 0; wg < 16; ++wg) t += mred[wg][csf][m * 4 + jf];
      atomicAdd(&S[mb[m] + n * 64 + tid], t);
    }
  }
}

// ---------------- K6: attention -> final BN -> NCHW fp32 out (LDS transpose) ----------------
// R13: reverted to the R11-proven version (R12's rewrite implicated in the +25-30us
// regression by subtraction). attn_channel + final BN params recomputed per-block (R9);
// 128B-run output stores (R11).
__global__ void k6_k(const u16* __restrict__ conv, const float* __restrict__ S,
                     const float* __restrict__ asp, float* __restrict__ out,
                     const float* __restrict__ gv, const float* __restrict__ bv,
                     const float* __restrict__ gn, const float* __restrict__ bn_) {
  __shared__ float t[128][65];
  __shared__ float svv[64], bvv[64], achb[64], sAv[64], bAv[64];
  const int tid = threadIdx.x, lane = tid & 63, wave = tid >> 6;
  const int n = blockIdx.x >> 9;
  const int hw0 = (blockIdx.x & 511) << 7;
  const long P0 = (long)blockIdx.x * 128;
  if (tid < 64) {
    const float inv = 1.f / 524288.f;
    float sm = 0.f, sq2 = 0.f;
#pragma unroll
    for (int sh = 0; sh < 4; ++sh) {
      sm += S[S_SUM + sh * 192 + 128 + tid];
      sq2 += S[S_SSQ + sh * 192 + 128 + tid];
    }
    float mean = sm * inv;
    float var = sq2 * inv - mean * mean;
    float rstd = rsqrtf(var + 1e-5f);
    float sv = gv[tid] * rstd;
    svv[tid] = sv;
    bvv[tid] = bv[tid] - mean * sv;
    const float smc = 1e-5f, cnt = 65536.f;
    float s1 = 0.f, s2 = 0.f, myach = 0.f;
#pragma unroll
    for (int nn = 0; nn < 8; ++nn) {
      int idx = nn * 64 + tid;
      float A1 = S[M_A1 + idx], A23 = S[M_A23 + idx], A45 = S[M_A45 + idx];
      float t1 = (A1 + smc) / (A23 - A1 + smc);
      float t2 = (cnt - A45 + A1 + smc) / (cnt - A45 + A23 - A1 + smc);
      float ach = 0.5f * (t1 + t2);
      if (nn == n) myach = ach;
      s1 += 0.5f * (S[M_AV + idx] + ach * S[M_V1 + idx]);
      s2 += 0.25f * (S[M_A2V2 + idx] + 2.f * ach * S[M_AV2 + idx] + ach * ach * S[M_V2 + idx]);
    }
    float mean2 = s1 * inv;
    float var2 = s2 * inv - mean2 * mean2;
    float rstd2 = rsqrtf(var2 + 1e-5f);
    float sA = gn[tid] * rstd2;
    sAv[tid] = sA;
    bAv[tid] = bn_[tid] - mean2 * sA;
    achb[tid] = myach;
  }
  __syncthreads();
  const float sv = svv[lane], bvx = bvv[lane];
  const float av = achb[lane];
  const float sA = sAv[lane], bA = bAv[lane];
  for (int i = wave; i < 128; i += 4) {
    const long p = P0 + i;
    float v = sigmoidf_(bf2f(conv[p * 192 + 128 + lane]) * sv + bvx);
    float att = 0.5f * (asp[p] + av) * v;
    t[i][lane] = att * sA + bA;
  }
  __syncthreads();
  const int c0 = tid >> 3, sub = tid & 7;   // 32 channels per pass, 8 x 16B = 128B runs
#pragma unroll
  for (int cl = 0; cl < 2; ++cl) {
    const int c = c0 + 32 * cl;
    const long plane = ((long)((n << 6) + c)) << 16;
#pragma unroll
    for (int i = 0; i < 4; ++i) {
      const int pst = (i * 8 + sub) << 2;
      f32x4 vbuf;
#pragma unroll
      for (int j = 0; j < 4; ++j) vbuf[j] = t[pst + j][c];
      *(f32x4*)(&out[plane + hw0 + pst]) = vbuf;
    }
  }
}

extern "C" void kernel_launch(void* const* d_in, const int* in_sizes, int n_in,
                              void* d_out, int out_size, void* d_ws, size_t ws_size,
                              hipStream_t stream) {
  (void)in_sizes; (void)n_in; (void)out_size; (void)ws_size;
  const float* x  = (const float*)d_in[0];
  const float* wq = (const float*)d_in[1];
  const float* gq = (const float*)d_in[2];
  const float* bq = (const float*)d_in[3];
  const float* wk = (const float*)d_in[4];
  const float* gk = (const float*)d_in[5];
  const float* bk = (const float*)d_in[6];
  const float* wv = (const float*)d_in[7];
  const float* gv = (const float*)d_in[8];
  const float* bv = (const float*)d_in[9];
  const float* gn = (const float*)d_in[10];
  const float* bn_ = (const float*)d_in[11];
  char* ws = (char*)d_ws;
  float* S   = (float*)(ws + OFF_SUMS);
  u16* wt    = (u16*)(ws + OFF_WT);
  float* asp = (float*)(ws + OFF_ASP);
  u16* conv  = (u16*)(ws + OFF_CONV);
  float* out = (float*)d_out;
  u16* xt  = (u16*)d_out;  // padded pre-swizzled bf16 scratch in d_out; overwritten by k6_k

  tr_k<<<4537, 256, 0, stream>>>(x, xt, wq, wk, wv, wt, S);
  conv_k<<<4096, 256, 0, stream>>>(xt, wt, conv, S);
  k3_k<<<4096, 256, 0, stream>>>(conv, S, asp, gq, bq, gk, bk, gv, bv);
  k6_k<<<4096, 256, 0, stream>>>(conv, S, asp, out, gv, bv, gn, bn_);
}

// Round 14
// 506.921 us; speedup vs baseline: 1.1297x; 1.1221x over previous
//
#include <hip/hip_runtime.h>

typedef unsigned short u16;
typedef __attribute__((ext_vector_type(4))) short short4v;
typedef __attribute__((ext_vector_type(8))) short short8;
typedef __attribute__((ext_vector_type(4))) float f32x4;
typedef __attribute__((ext_vector_type(16))) float f32x16;

// ---- ws layout (bytes) ----
#define OFF_SUMS 0ul              // 6656 floats = 26624
#define OFF_WT   26624ul          // 110592*2 = 221184 : weights bf16, fragment-major (see tr_k)
#define OFF_ASP  247808ul         // 524288*4 = 2097152 : attn_spatial fp32 [pixel]
#define OFF_CONV 2344960ul        // 524288*192*2 = 201326592 : raw conv out bf16 [pixel][192]
// xt (padded NHWC bf16 [8][258][258][64] = 68.2 MB, granule-swizzled) lives in d_out (134 MB);
// k6 overwrites it.
// ---- S (float) offsets ----
#define S_SUM   0      // conv channel sums, 4 shadows x 192
#define S_SSQ   768    // conv channel ssq, 4 shadows x 192
#define M_A1    1920   // per (n*64+c): sum q*k        [512]
#define M_A23   2432   // sum q^2+k^2                  [512]
#define M_A45   2944   // sum q+k                      [512]
#define M_V1    3456   // sum v                        [512]
#define M_V2    3968   // sum v^2                      [512]
#define M_AV    4480   // sum asp*v                    [512]
#define M_AV2   4992   // sum asp*v^2                  [512]
#define M_A2V2  5504   // sum asp^2*v^2                [512]
#define S_NFLOAT 6656

__device__ __forceinline__ float bf2f(u16 v) {
  union { unsigned u; float f; } x; x.u = ((unsigned)v) << 16; return x.f;
}
__device__ __forceinline__ u16 f2bf(float f) {
  union { float f; unsigned u; } x; x.f = f;
  unsigned r = x.u + 0x7fffu + ((x.u >> 16) & 1u);
  return (u16)(r >> 16);
}
// v_rcp_f32: ~1 ulp approx reciprocal; error 1e-7 rel, negligible vs bf16 data path (0.4%).
__device__ __forceinline__ float frcp(float x) { return __builtin_amdgcn_rcpf(x); }
__device__ __forceinline__ float sigmoidf_(float x) { return frcp(1.f + __expf(-x)); }

// ---- DPP wave64 sum (all-VALU, zero DS ops) ----
template <int CTRL, int RMASK>
__device__ __forceinline__ float dpp_add(float x) {
  int m = __builtin_amdgcn_update_dpp(0, __builtin_bit_cast(int, x), CTRL, RMASK, 0xf, true);
  return x + __builtin_bit_cast(float, m);
}
__device__ __forceinline__ float wsum64(float x) {
  x = dpp_add<0x111, 0xf>(x);  // row_shr:1
  x = dpp_add<0x112, 0xf>(x);  // row_shr:2
  x = dpp_add<0x114, 0xf>(x);  // row_shr:4
  x = dpp_add<0x118, 0xf>(x);  // row_shr:8
  x = dpp_add<0x142, 0xa>(x);  // row_bcast:15 -> rows 1,3
  x = dpp_add<0x143, 0xc>(x);  // row_bcast:31 -> rows 2,3
  return __builtin_bit_cast(float, __builtin_amdgcn_readlane(__builtin_bit_cast(int, x), 63));
}

// ---------------- K0: transpose (0..4095) + halo-zero (4096..4103) + repack (4104..4535)
//                   + S-zero (4536) ----------
// xt is PADDED [n][258][258][64] with a 1-px zero border; each 128B pixel row is stored with
// its 16B granules XOR-swizzled by (padded_col & 7). conv_k stages with global_load_lds
// (linear LDS dest + pre-swizzled source + swizzled read).
__global__ void tr_k(const float* __restrict__ x, u16* __restrict__ xt,
                     const float* __restrict__ wq, const float* __restrict__ wk,
                     const float* __restrict__ wv, u16* __restrict__ wt,
                     float* __restrict__ S) {
  const int bid = blockIdx.x;
  const int tid = threadIdx.x;
  if (bid == 4536) {  // ---- S-zero branch ----
    for (int i = tid; i < S_NFLOAT; i += 256) S[i] = 0.f;
    return;
  }
  if (bid >= 4104) {  // ---- repack branch ----
    int i = (bid - 4104) * 256 + tid;
    if (i >= 110592) return;
    int j = i & 7, l = (i >> 3) & 63, kc = (i >> 9) & 3;
    int t2 = i >> 11;              // dydx*6 + ocg
    int ocg = t2 % 6, dydx = t2 / 6;
    int oc = ocg * 32 + (l & 31);
    int ch = kc * 16 + (l >> 5) * 8 + j;
    int cs = oc >> 6, ol = oc & 63;
    const float* src = cs == 0 ? wq : (cs == 1 ? wk : wv);
    wt[i] = f2bf(src[(ol * 64 + ch) * 9 + dydx]);
    return;
  }
  if (bid >= 4096) {  // ---- halo-zero branch: 1-px border of padded image n ----
    const int n = bid - 4096;
    const uint4 z = make_uint4(0u, 0u, 0u, 0u);
    for (int t = tid; t < 8224; t += 256) {
      int cell = t >> 3, g = t & 7;
      int row, col;
      if (cell < 258) { row = 0; col = cell; }
      else if (cell < 516) { row = 257; col = cell - 258; }
      else if (cell < 772) { row = cell - 516 + 1; col = 0; }
      else { row = cell - 772 + 1; col = 257; }
      *(uint4*)(xt + ((long)(n * 258 + row) * 258 + col) * 64 + (g << 3)) = z;
    }
    return;
  }
  // ---- transpose branch (vectorized, R9) ----
  __shared__ u16 t[64][130];
  const int wtile = bid & 1, h = (bid >> 1) & 255, n = bid >> 9;
  const int w0 = wtile << 7;
#pragma unroll
  for (int it = 0; it < 8; ++it) {
    int i = it * 256 + tid;
    int c = i >> 5, w4 = (i & 31) << 2;
    const f32x4 v = *(const f32x4*)(&x[(((long)((n << 6) + c)) << 16) + (h << 8) + w0 + w4]);
    unsigned p0 = (unsigned)f2bf(v[0]) | ((unsigned)f2bf(v[1]) << 16);
    unsigned p1 = (unsigned)f2bf(v[2]) | ((unsigned)f2bf(v[3]) << 16);
    *(unsigned*)(&t[c][w4]) = p0;
    *(unsigned*)(&t[c][w4 + 2]) = p1;
  }
  __syncthreads();
#pragma unroll
  for (int it = 0; it < 4; ++it) {
    int i = it * 256 + tid;
    int g = i & 7, w = i >> 3;          // granule g = channels g*8..g*8+7, col w
    int c8 = g << 3;
    unsigned short u[8];
#pragma unroll
    for (int j = 0; j < 8; ++j) u[j] = t[c8 + j][w];
    uint4 val;
    val.x = (unsigned)u[0] | ((unsigned)u[1] << 16);
    val.y = (unsigned)u[2] | ((unsigned)u[3] << 16);
    val.z = (unsigned)u[4] | ((unsigned)u[5] << 16);
    val.w = (unsigned)u[6] | ((unsigned)u[7] << 16);
    const int pw = w0 + w + 1;          // padded col
    const int gs = g ^ (pw & 7);        // pre-swizzled granule
    *(uint4*)(xt + ((long)(n * 258 + h + 1) * 258 + pw) * 64 + (gs << 3)) = val;
  }
}

// ---------------- K1: fused QKV conv3x3 as implicit GEMM (MFMA bf16) + channel stats ----------------
// R11 (unchanged, control): global_load_lds staging + hoisted tap-(0,0) B prefetch.
__global__ __launch_bounds__(256, 2) void conv_k(const u16* __restrict__ xt,
                                                 const u16* __restrict__ wt,
                                                 u16* __restrict__ conv,
                                                 float* __restrict__ S) {
  __shared__ u16 lx[3 * 8704];  // 3 strips * 136 px * 64 ch = 52224 B (px 130..135 unused)
  const int bid = blockIdx.x;
  const int wtile = bid & 1, h = (bid >> 1) & 255, n = bid >> 9;
  const int w0 = wtile << 7;
  const int tid = threadIdx.x;
  const int lane = tid & 63, wave = tid >> 6;
  const int l31 = lane & 31, half = lane >> 5;
  const int wm = wave & 1, wn = wave >> 1;  // wm: px half (64), wn: oc group (96)
  {
    // strip s: padded row h+s (= global rows h-1..h+1), padded cols w0.. (= global w0-1..)
    const long rowbase = ((long)(n * 258 + h) * 258 + w0) * 64;
    for (int c = wave; c < 51; c += 4) {
      const int s = (c >= 34) ? 2 : (c >= 17 ? 1 : 0);
      const int lc = c - s * 17;
      const int loff = s * 8704 + lc * 512 + lane * 8;
      const long goff = rowbase + (long)s * 16512 + lc * 512 + lane * 8;  // 258*64=16512
      __builtin_amdgcn_global_load_lds(
          (const __attribute__((address_space(1))) unsigned int*)(xt + goff),
          (__attribute__((address_space(3))) unsigned int*)(&lx[loff]), 16, 0, 0);
    }
  }
  // prefetch tap-(0,0) B fragments before the barrier (independent of LDS staging)
  short8 bfr0[3][4];
#pragma unroll
  for (int nt = 0; nt < 3; ++nt)
#pragma unroll
    for (int kc = 0; kc < 4; ++kc)
      bfr0[nt][kc] = *(const short8*)(wt + ((wn * 3 + nt) * 4 + kc) * 512 + lane * 8);
  __syncthreads();
  f32x16 acc[3][2];
#pragma unroll
  for (int a = 0; a < 3; ++a)
#pragma unroll
    for (int b = 0; b < 2; ++b)
#pragma unroll
      for (int e = 0; e < 16; ++e) acc[a][b][e] = 0.f;

#pragma unroll
  for (int dy = 0; dy < 3; ++dy) {
#pragma unroll
    for (int dx = 0; dx < 3; ++dx) {
      const u16* wp = wt + (dy * 3 + dx) * 12288;
      short8 bfr[3][4];
#pragma unroll
      for (int nt = 0; nt < 3; ++nt)
#pragma unroll
        for (int kc = 0; kc < 4; ++kc)
          bfr[nt][kc] = (dy == 0 && dx == 0) ? bfr0[nt][kc]
                        : *(const short8*)(wp + ((wn * 3 + nt) * 4 + kc) * 512 + lane * 8);
#pragma unroll
      for (int kc = 0; kc < 4; ++kc) {
        short8 afr[2];
#pragma unroll
        for (int mt = 0; mt < 2; ++mt) {
          const int px = wm * 64 + mt * 32 + l31 + dx;       // staged col (0..129)
          const int chb = kc * 16 + half * 8;                // k-slice base channel
          int idx = ((px << 6) + chb) ^ ((px & 7) << 3);
          afr[mt] = *(const short8*)(&lx[dy * 8704 + idx]);
        }
#pragma unroll
        for (int mt = 0; mt < 2; ++mt)
#pragma unroll
          for (int nt = 0; nt < 3; ++nt)
            acc[nt][mt] = __builtin_amdgcn_mfma_f32_32x32x16_bf16(afr[mt], bfr[nt][kc], acc[nt][mt], 0, 0, 0);
      }
    }
  }
  // epilogue: C col = l31 (oc), row = (r&3) + 8*(r>>2) + 4*half (px); store bf16 [pixel][192]
  const long pix0 = (long)bid * 128 + wm * 64;
#pragma unroll
  for (int nt = 0; nt < 3; ++nt) {
    const int oc = wn * 96 + nt * 32 + l31;
#pragma unroll
    for (int mt = 0; mt < 2; ++mt) {
      const long pxb = pix0 + mt * 32 + half * 4;
#pragma unroll
      for (int rq = 0; rq < 4; ++rq)
#pragma unroll
        for (int rr = 0; rr < 4; ++rr) {
          const long px = pxb + rr + 8 * rq;
          conv[px * 192 + oc] = f2bf(acc[nt][mt][rq * 4 + rr]);
        }
    }
  }
  // fused per-channel stats
  const int sh = (bid & 3) * 192;
#pragma unroll
  for (int nt = 0; nt < 3; ++nt) {
    float s = 0.f, ss = 0.f;
#pragma unroll
    for (int mt = 0; mt < 2; ++mt)
#pragma unroll
      for (int r = 0; r < 16; ++r) {
        float x = acc[nt][mt][r];
        s += x; ss += x * x;
      }
    s += __shfl_xor(s, 32); ss += __shfl_xor(ss, 32);
    if (lane < 32) {
      const int oc = wn * 96 + nt * 32 + lane;
      atomicAdd(&S[S_SUM + sh + oc], s);
      atomicAdd(&S[S_SSQ + sh + oc], ss);
    }
  }
}

// ---------------- K3: BN+sigmoid q,k,v; asp per pixel; 8 moments per (n,c) ----------------
// R14: reverted to the R11-proven scalar+wsum64 version. Both vectorized rewrites (R12 8-ch
// spill, R13 4-ch) measured ~+30us vs this -- the scalar loads were already TLP-hidden.
__global__ void k3_k(const u16* __restrict__ conv, float* __restrict__ S, float* __restrict__ asp,
                     const float* __restrict__ gq, const float* __restrict__ bq,
                     const float* __restrict__ gk, const float* __restrict__ bk,
                     const float* __restrict__ gv, const float* __restrict__ bv) {
  __shared__ float red[4][8][64];
  __shared__ float scb[192], bib[192];
  const int tid = threadIdx.x, lane = tid & 63, wave = tid >> 6;
  const int bid = blockIdx.x;          // 4096 blocks x 128 px
  const int n = bid >> 9;
  const long p0 = (long)bid * 128 + wave * 32;
  if (tid < 192) {
    int cv = tid >> 6, c = tid & 63;
    float g = cv == 0 ? gq[c] : (cv == 1 ? gk[c] : gv[c]);
    float b = cv == 0 ? bq[c] : (cv == 1 ? bk[c] : bv[c]);
    float sm = 0.f, sq2 = 0.f;
#pragma unroll
    for (int sh = 0; sh < 4; ++sh) { sm += S[S_SUM + sh * 192 + tid]; sq2 += S[S_SSQ + sh * 192 + tid]; }
    const float inv = 1.f / 524288.f;
    float mean = sm * inv;
    float var = sq2 * inv - mean * mean;
    float rstd = rsqrtf(var + 1e-5f);
    float sc = g * rstd;
    scb[tid] = sc;
    bib[tid] = b - mean * sc;
  }
  __syncthreads();
  const float sq = scb[lane], bq_ = bib[lane];
  const float sk = scb[64 + lane], bk_ = bib[64 + lane];
  const float sv = scb[128 + lane], bv_ = bib[128 + lane];
  float A1 = 0.f, A23 = 0.f, A45 = 0.f, V1 = 0.f, V2 = 0.f, AV = 0.f, AV2 = 0.f, A2V2 = 0.f;
  float myasp = 0.f;
#pragma unroll 4
  for (int i = 0; i < 32; ++i) {
    const u16* row = conv + (p0 + i) * 192;
    float q = sigmoidf_(bf2f(row[lane]) * sq + bq_);
    float k = sigmoidf_(bf2f(row[64 + lane]) * sk + bk_);
    float v = sigmoidf_(bf2f(row[128 + lane]) * sv + bv_);
    float p1 = q * k, p23 = q * q + k * k, p45 = q + k;
    A1 += p1; A23 += p23; A45 += p45;
    float s1 = wsum64(p1);
    float s23 = wsum64(p23);
    float s45 = wsum64(p45);
    const float sm = 1e-5f;
    float t1 = (s1 + sm) * frcp(s23 - s1 + sm);
    float t2 = (64.f - s45 + s1 + sm) * frcp(64.f - s45 + s23 - s1 + sm);
    float a = 0.5f * (t1 + t2);
    if (i == (lane & 31)) myasp = a;
    float av = a * v;
    V1 += v; V2 += v * v; AV += av; AV2 += av * v; A2V2 += av * av;
  }
  if (lane < 32) asp[p0 + lane] = myasp;
  red[wave][0][lane] = A1;  red[wave][1][lane] = A23; red[wave][2][lane] = A45;
  red[wave][3][lane] = V1;  red[wave][4][lane] = V2;  red[wave][5][lane] = AV;
  red[wave][6][lane] = AV2; red[wave][7][lane] = A2V2;
  __syncthreads();
  if (tid < 64) {
    const int mb[8] = {M_A1, M_A23, M_A45, M_V1, M_V2, M_AV, M_AV2, M_A2V2};
#pragma unroll
    for (int m = 0; m < 8; ++m) {
      float t = red[0][m][tid] + red[1][m][tid] + red[2][m][tid] + red[3][m][tid];
      atomicAdd(&S[mb[m] + n * 64 + tid], t);
    }
  }
}

// ---------------- K6: attention -> final BN -> NCHW fp32 out (LDS transpose) ----------------
// R14: R11's structure with ONLY the fill loop vectorized: lane = (r = lane>>4, cs4 = lane&15),
// 4 rows per wave-iter, short4 v-loads (coalesced 4x128B/wave) -- 16 VMEM/thread vs 64.
// LDS tile stride 65 -> 68 floats for aligned f32x4 stores (phase-2 pattern as R12, proven).
// Output phase byte-identical to R11 (128B runs).
__global__ void k6_k(const u16* __restrict__ conv, const float* __restrict__ S,
                     const float* __restrict__ asp, float* __restrict__ out,
                     const float* __restrict__ gv, const float* __restrict__ bv,
                     const float* __restrict__ gn, const float* __restrict__ bn_) {
  __shared__ float t[128][68];
  __shared__ float svv[64], bvv[64], achb[64], sAv[64], bAv[64];
  const int tid = threadIdx.x, lane = tid & 63, wave = tid >> 6;
  const int n = blockIdx.x >> 9;
  const int hw0 = (blockIdx.x & 511) << 7;
  const long P0 = (long)blockIdx.x * 128;
  if (tid < 64) {
    const float inv = 1.f / 524288.f;
    float sm = 0.f, sq2 = 0.f;
#pragma unroll
    for (int sh = 0; sh < 4; ++sh) {
      sm += S[S_SUM + sh * 192 + 128 + tid];
      sq2 += S[S_SSQ + sh * 192 + 128 + tid];
    }
    float mean = sm * inv;
    float var = sq2 * inv - mean * mean;
    float rstd = rsqrtf(var + 1e-5f);
    float sv = gv[tid] * rstd;
    svv[tid] = sv;
    bvv[tid] = bv[tid] - mean * sv;
    const float smc = 1e-5f, cnt = 65536.f;
    float s1 = 0.f, s2 = 0.f, myach = 0.f;
#pragma unroll
    for (int nn = 0; nn < 8; ++nn) {
      int idx = nn * 64 + tid;
      float A1 = S[M_A1 + idx], A23 = S[M_A23 + idx], A45 = S[M_A45 + idx];
      float t1 = (A1 + smc) / (A23 - A1 + smc);
      float t2 = (cnt - A45 + A1 + smc) / (cnt - A45 + A23 - A1 + smc);
      float ach = 0.5f * (t1 + t2);
      if (nn == n) myach = ach;
      s1 += 0.5f * (S[M_AV + idx] + ach * S[M_V1 + idx]);
      s2 += 0.25f * (S[M_A2V2 + idx] + 2.f * ach * S[M_AV2 + idx] + ach * ach * S[M_V2 + idx]);
    }
    float mean2 = s1 * inv;
    float var2 = s2 * inv - mean2 * mean2;
    float rstd2 = rsqrtf(var2 + 1e-5f);
    float sA = gn[tid] * rstd2;
    sAv[tid] = sA;
    bAv[tid] = bn_[tid] - mean2 * sA;
    achb[tid] = myach;
  }
  __syncthreads();
  const int r = lane >> 4, cs4 = lane & 15;
  float sv4[4], bv4[4], av4[4], sA4[4], bA4[4];
#pragma unroll
  for (int j = 0; j < 4; ++j) {
    int c = cs4 * 4 + j;
    sv4[j] = svv[c]; bv4[j] = bvv[c]; av4[j] = achb[c]; sA4[j] = sAv[c]; bA4[j] = bAv[c];
  }
#pragma unroll
  for (int i = 0; i < 8; ++i) {
    const int px = i * 16 + wave * 4 + r;
    const long p = P0 + px;
    short4v vv = *(const short4v*)(conv + p * 192 + 128 + cs4 * 4);
    float aspv = asp[p];
    f32x4 ov;
#pragma unroll
    for (int j = 0; j < 4; ++j) {
      float v = sigmoidf_(bf2f((u16)vv[j]) * sv4[j] + bv4[j]);
      float att = 0.5f * (aspv + av4[j]) * v;
      ov[j] = att * sA4[j] + bA4[j];
    }
    *(f32x4*)(&t[px][cs4 * 4]) = ov;
  }
  __syncthreads();
  const int c0 = tid >> 3, sub = tid & 7;   // 32 channels per pass, 8 x 16B = 128B runs
#pragma unroll
  for (int cl = 0; cl < 2; ++cl) {
    const int c = c0 + 32 * cl;
    const long plane = ((long)((n << 6) + c)) << 16;
#pragma unroll
    for (int i = 0; i < 4; ++i) {
      const int pst = (i * 8 + sub) << 2;
      f32x4 vbuf;
#pragma unroll
      for (int j = 0; j < 4; ++j) vbuf[j] = t[pst + j][c];
      *(f32x4*)(&out[plane + hw0 + pst]) = vbuf;
    }
  }
}

extern "C" void kernel_launch(void* const* d_in, const int* in_sizes, int n_in,
                              void* d_out, int out_size, void* d_ws, size_t ws_size,
                              hipStream_t stream) {
  (void)in_sizes; (void)n_in; (void)out_size; (void)ws_size;
  const float* x  = (const float*)d_in[0];
  const float* wq = (const float*)d_in[1];
  const float* gq = (const float*)d_in[2];
  const float* bq = (const float*)d_in[3];
  const float* wk = (const float*)d_in[4];
  const float* gk = (const float*)d_in[5];
  const float* bk = (const float*)d_in[6];
  const float* wv = (const float*)d_in[7];
  const float* gv = (const float*)d_in[8];
  const float* bv = (const float*)d_in[9];
  const float* gn = (const float*)d_in[10];
  const float* bn_ = (const float*)d_in[11];
  char* ws = (char*)d_ws;
  float* S   = (float*)(ws + OFF_SUMS);
  u16* wt    = (u16*)(ws + OFF_WT);
  float* asp = (float*)(ws + OFF_ASP);
  u16* conv  = (u16*)(ws + OFF_CONV);
  float* out = (float*)d_out;
  u16* xt  = (u16*)d_out;  // padded pre-swizzled bf16 scratch in d_out; overwritten by k6_k

  tr_k<<<4537, 256, 0, stream>>>(x, xt, wq, wk, wv, wt, S);
  conv_k<<<4096, 256, 0, stream>>>(xt, wt, conv, S);
  k3_k<<<4096, 256, 0, stream>>>(conv, S, asp, gq, bq, gk, bk, gv, bv);
  k6_k<<<4096, 256, 0, stream>>>(conv, S, asp, out, gv, bv, gn, bn_);
}